// Round 16
// baseline (61.289 us; speedup 1.0000x reference)
//
#include <hip/hip_runtime.h>
#include <math.h>

// WindingEmbedding: rows = 32768 (B=8, S=4096), D=1024, W=8 windings, F=16 feats.
// out[row][d] = ((emb - mu) * rsqrt(var+eps)) * gamma + beta
// emb[row][d] = sum_f feats[row][f] * pw[d][f] + pb[d]
//
// Analytic LayerNorm stats:
//   mu = f.meanW + mean_b ; E[e^2] = f'Mf + 2 f.c + mean_b2 ; var = E[e^2]-mu^2
// with M = (1/D) W'W, meanW = (1/D) W'1, c = (1/D) W'b.
//
// SINGLE dispatch. Insight: a 512-block/256-thr grid where thread t register-
// caches pw rows 4t..4t+3 already holds the ENTIRE weight matrix in registers
// per block -> M computed in-register: 136 upper-tri entries split 34/wave,
// 4-sub-phase rotation (wave w does entry-set (w+p)&3 over ITS 256 rows),
// 64-lane butterfly, lane0 -> LDS wave-partials, 136 threads combine.
// All register indices are compile-time literals (macro-unrolled).
// Ledger: NT stores bad (R5/R9); cross-XCD partial reads bad (R8/R11/R12);
// grid.sync ~70us (R13); gathers bad (R14); dispatch overhead ~1us (R13).

#define TWO_PI 6.28318530717958647692f
#define INV_VOCAB (1.0f / 50257.0f)
#define INV_D (1.0f / 1024.0f)
#define ROWS_PB 64

typedef float f32x4 __attribute__((ext_vector_type(4)));

// element (row r, col c) of this thread's cached pw rows; c must be a literal
#define WEL(r, c)                                                          \
  (((c) & 3) == 0   ? wreg[r][(c) >> 2].x                                  \
   : ((c) & 3) == 1 ? wreg[r][(c) >> 2].y                                  \
   : ((c) & 3) == 2 ? wreg[r][(c) >> 2].z                                  \
                    : wreg[r][(c) >> 2].w)

#define ME(s, j, i)                                                        \
  acc[s] = fmaf(WEL(3, j), WEL(3, i),                                      \
           fmaf(WEL(2, j), WEL(2, i),                                      \
           fmaf(WEL(1, j), WEL(1, i), WEL(0, j) * WEL(0, i))));

__global__ __launch_bounds__(256) void wind_one(const int* __restrict__ x,
                                                const float* __restrict__ winds,
                                                const float* __restrict__ pw,
                                                const float* __restrict__ pb,
                                                const float* __restrict__ gamma,
                                                const float* __restrict__ beta,
                                                float* __restrict__ out) {
  __shared__ __align__(16) float feat[ROWS_PB][20];  // 16B-aligned rows
  __shared__ __align__(16) float Mlds[16][20];       // b128-loadable M rows
  __shared__ float Mwp[4][4][34];                    // [set][wave][slot]
  __shared__ float Vwp[4][34];                       // [wave][slot] meanW|c|b1|b2
  __shared__ float mwl[16], cl[16], cst[2];
  __shared__ float murs[ROWS_PB][2];

  const int tid = threadIdx.x;
  const int wave = tid >> 6;
  const int lane = tid & 63;
  const int row0 = blockIdx.x * ROWS_PB;

  // early: x loads for feat staging (hide latency under stats compute)
  float tfv[4];
#pragma unroll
  for (int s = 0; s < 4; ++s)
    tfv[s] = (float)x[row0 + ((tid + s * 256) >> 4)] * INV_VOCAB;

  // this thread's 4 projection rows (dims 4t..4t+3) + bias/affine
  float4 wreg[4][4];
#pragma unroll
  for (int r = 0; r < 4; ++r)
#pragma unroll
    for (int c = 0; c < 4; ++c)
      wreg[r][c] = reinterpret_cast<const float4*>(pw)[(tid * 4 + r) * 4 + c];
  const float4 pbv = reinterpret_cast<const float4*>(pb)[tid];
  const float4 gv = reinterpret_cast<const float4*>(gamma)[tid];
  const float4 bv = reinterpret_cast<const float4*>(beta)[tid];

  // ---- vector stats (meanW, c, b1, b2): 34 values, all waves, register-only ----
  {
    float v[34];
#pragma unroll
    for (int c = 0; c < 16; ++c) {
      v[c] = (WEL(0, c) + WEL(1, c)) + (WEL(2, c) + WEL(3, c));
      v[16 + c] = fmaf(WEL(0, c), pbv.x, fmaf(WEL(1, c), pbv.y,
                  fmaf(WEL(2, c), pbv.z, WEL(3, c) * pbv.w)));
    }
    v[32] = (pbv.x + pbv.y) + (pbv.z + pbv.w);
    v[33] = fmaf(pbv.x, pbv.x, fmaf(pbv.y, pbv.y, fmaf(pbv.z, pbv.z, pbv.w * pbv.w)));
#pragma unroll
    for (int s = 0; s < 34; ++s)
#pragma unroll
      for (int off = 1; off < 64; off <<= 1) v[s] += __shfl_xor(v[s], off);
    if (lane == 0)
#pragma unroll
      for (int s = 0; s < 34; ++s) Vwp[wave][s] = v[s];
  }

  // ---- M entries: 136 upper-tri, 34/set, 4-sub-phase rotation ----
#pragma unroll 1
  for (int p = 0; p < 4; ++p) {
    const int set = (wave + p) & 3;
    float acc[34];
    if (set == 0) {
      ME(0,0,0) ME(1,0,1) ME(2,0,2) ME(3,0,3) ME(4,0,4) ME(5,0,5) ME(6,0,6)
      ME(7,0,7) ME(8,0,8) ME(9,0,9) ME(10,0,10) ME(11,0,11) ME(12,0,12)
      ME(13,0,13) ME(14,0,14) ME(15,0,15)
      ME(16,1,1) ME(17,1,2) ME(18,1,3) ME(19,1,4) ME(20,1,5) ME(21,1,6)
      ME(22,1,7) ME(23,1,8) ME(24,1,9) ME(25,1,10) ME(26,1,11) ME(27,1,12)
      ME(28,1,13) ME(29,1,14) ME(30,1,15)
      ME(31,2,2) ME(32,2,3) ME(33,2,4)
    } else if (set == 1) {
      ME(0,2,5) ME(1,2,6) ME(2,2,7) ME(3,2,8) ME(4,2,9) ME(5,2,10) ME(6,2,11)
      ME(7,2,12) ME(8,2,13) ME(9,2,14) ME(10,2,15)
      ME(11,3,3) ME(12,3,4) ME(13,3,5) ME(14,3,6) ME(15,3,7) ME(16,3,8)
      ME(17,3,9) ME(18,3,10) ME(19,3,11) ME(20,3,12) ME(21,3,13) ME(22,3,14)
      ME(23,3,15)
      ME(24,4,4) ME(25,4,5) ME(26,4,6) ME(27,4,7) ME(28,4,8) ME(29,4,9)
      ME(30,4,10) ME(31,4,11) ME(32,4,12) ME(33,4,13)
    } else if (set == 2) {
      ME(0,4,14) ME(1,4,15)
      ME(2,5,5) ME(3,5,6) ME(4,5,7) ME(5,5,8) ME(6,5,9) ME(7,5,10) ME(8,5,11)
      ME(9,5,12) ME(10,5,13) ME(11,5,14) ME(12,5,15)
      ME(13,6,6) ME(14,6,7) ME(15,6,8) ME(16,6,9) ME(17,6,10) ME(18,6,11)
      ME(19,6,12) ME(20,6,13) ME(21,6,14) ME(22,6,15)
      ME(23,7,7) ME(24,7,8) ME(25,7,9) ME(26,7,10) ME(27,7,11) ME(28,7,12)
      ME(29,7,13) ME(30,7,14) ME(31,7,15)
      ME(32,8,8) ME(33,8,9)
    } else {
      ME(0,8,10) ME(1,8,11) ME(2,8,12) ME(3,8,13) ME(4,8,14) ME(5,8,15)
      ME(6,9,9) ME(7,9,10) ME(8,9,11) ME(9,9,12) ME(10,9,13) ME(11,9,14)
      ME(12,9,15)
      ME(13,10,10) ME(14,10,11) ME(15,10,12) ME(16,10,13) ME(17,10,14)
      ME(18,10,15)
      ME(19,11,11) ME(20,11,12) ME(21,11,13) ME(22,11,14) ME(23,11,15)
      ME(24,12,12) ME(25,12,13) ME(26,12,14) ME(27,12,15)
      ME(28,13,13) ME(29,13,14) ME(30,13,15)
      ME(31,14,14) ME(32,14,15)
      ME(33,15,15)
    }
#pragma unroll
    for (int s = 0; s < 34; ++s)
#pragma unroll
      for (int off = 1; off < 64; off <<= 1) acc[s] += __shfl_xor(acc[s], off);
    if (lane == 0)
#pragma unroll
      for (int s = 0; s < 34; ++s) Mwp[set][wave][s] = acc[s];
  }

  // ---- feat staging: 64 rows x 16 feats, 4 sincos/thread ----
#pragma unroll
  for (int s = 0; s < 4; ++s) {
    const int slot = tid + s * 256;
    const int r = slot >> 4, jj = slot & 15;
    float sn, cs;
    sincosf(TWO_PI * tfv[s] * winds[jj >> 1], &sn, &cs);
    feat[r][jj] = (jj & 1) ? sn : cs;  // [cos0,sin0,cos1,sin1,...]
  }
  __syncthreads();

  // ---- combine wave-partials -> Mlds / mwl / cl / cst ----
  if (tid < 136) {
    const int set = tid / 34, sl = tid - set * 34;
    const float val = ((Mwp[set][0][sl] + Mwp[set][1][sl]) +
                       (Mwp[set][2][sl] + Mwp[set][3][sl])) * INV_D;
    int e = tid, j = 0;
    while (e >= 16 - j) { e -= 16 - j; ++j; }
    const int i = j + e;
    Mlds[j][i] = val;
    Mlds[i][j] = val;
  } else if (tid < 170) {
    const int sl = tid - 136;
    const float val = ((Vwp[0][sl] + Vwp[1][sl]) +
                       (Vwp[2][sl] + Vwp[3][sl])) * INV_D;
    if (sl < 16) mwl[sl] = val;
    else if (sl < 32) cl[sl - 16] = val;
    else cst[sl - 32] = val;
  }
  __syncthreads();

  // ---- per-row stats: 16-lane group per row, 4 rows/thread, in-wave ----
  {
    const int jj = tid & 15;
    const float mwj = mwl[jj];
    const float cj = cl[jj];
    const f32x4 M0 = *reinterpret_cast<const f32x4*>(&Mlds[jj][0]);
    const f32x4 M1 = *reinterpret_cast<const f32x4*>(&Mlds[jj][4]);
    const f32x4 M2 = *reinterpret_cast<const f32x4*>(&Mlds[jj][8]);
    const f32x4 M3 = *reinterpret_cast<const f32x4*>(&Mlds[jj][12]);
#pragma unroll
    for (int h = 0; h < 4; ++h) {
      const int r = (tid >> 4) + h * 16;
      const f32x4 F0 = *reinterpret_cast<const f32x4*>(&feat[r][0]);
      const f32x4 F1 = *reinterpret_cast<const f32x4*>(&feat[r][4]);
      const f32x4 F2 = *reinterpret_cast<const f32x4*>(&feat[r][8]);
      const f32x4 F3 = *reinterpret_cast<const f32x4*>(&feat[r][12]);
      float acc = 0.f;
      acc = fmaf(M0.x, F0.x, acc); acc = fmaf(M0.y, F0.y, acc);
      acc = fmaf(M0.z, F0.z, acc); acc = fmaf(M0.w, F0.w, acc);
      acc = fmaf(M1.x, F1.x, acc); acc = fmaf(M1.y, F1.y, acc);
      acc = fmaf(M1.z, F1.z, acc); acc = fmaf(M1.w, F1.w, acc);
      acc = fmaf(M2.x, F2.x, acc); acc = fmaf(M2.y, F2.y, acc);
      acc = fmaf(M2.z, F2.z, acc); acc = fmaf(M2.w, F2.w, acc);
      acc = fmaf(M3.x, F3.x, acc); acc = fmaf(M3.y, F3.y, acc);
      acc = fmaf(M3.z, F3.z, acc); acc = fmaf(M3.w, F3.w, acc);
      const float fjj = feat[r][jj];
      float pE = fjj * fmaf(2.f, cj, acc);
      float pM = fjj * mwj;
#pragma unroll
      for (int off = 1; off < 16; off <<= 1) {
        pE += __shfl_xor(pE, off);
        pM += __shfl_xor(pM, off);
      }
      if (jj == 0) {
        const float mu = pM + cst[0];
        const float var = (pE + cst[1]) - mu * mu;
        murs[r][0] = mu;
        murs[r][1] = rsqrtf(var + 1e-5f);
      }
    }
  }
  __syncthreads();

  // ---- store loop: 64 rows x 4 dims/thread; broadcast feat reads ----
  float* o = out + (size_t)row0 * 1024 + tid * 4;
#pragma unroll 2
  for (int r = 0; r < ROWS_PB; ++r) {
    const f32x4 F0 = *reinterpret_cast<const f32x4*>(&feat[r][0]);
    const f32x4 F1 = *reinterpret_cast<const f32x4*>(&feat[r][4]);
    const f32x4 F2 = *reinterpret_cast<const f32x4*>(&feat[r][8]);
    const f32x4 F3 = *reinterpret_cast<const f32x4*>(&feat[r][12]);
    float e[4];
#pragma unroll
    for (int k = 0; k < 4; ++k) {
      float a = (k == 0) ? pbv.x : (k == 1) ? pbv.y : (k == 2) ? pbv.z : pbv.w;
      a = fmaf(wreg[k][0].x, F0.x, a);
      a = fmaf(wreg[k][0].y, F0.y, a);
      a = fmaf(wreg[k][0].z, F0.z, a);
      a = fmaf(wreg[k][0].w, F0.w, a);
      a = fmaf(wreg[k][1].x, F1.x, a);
      a = fmaf(wreg[k][1].y, F1.y, a);
      a = fmaf(wreg[k][1].z, F1.z, a);
      a = fmaf(wreg[k][1].w, F1.w, a);
      a = fmaf(wreg[k][2].x, F2.x, a);
      a = fmaf(wreg[k][2].y, F2.y, a);
      a = fmaf(wreg[k][2].z, F2.z, a);
      a = fmaf(wreg[k][2].w, F2.w, a);
      a = fmaf(wreg[k][3].x, F3.x, a);
      a = fmaf(wreg[k][3].y, F3.y, a);
      a = fmaf(wreg[k][3].z, F3.z, a);
      a = fmaf(wreg[k][3].w, F3.w, a);
      e[k] = a;
    }
    const float mu = murs[r][0];
    const float rs = murs[r][1];
    const float s0 = gv.x * rs, s1 = gv.y * rs, s2 = gv.z * rs, s3 = gv.w * rs;
    f32x4 res;
    res.x = fmaf(e[0], s0, fmaf(-mu, s0, bv.x));
    res.y = fmaf(e[1], s1, fmaf(-mu, s1, bv.y));
    res.z = fmaf(e[2], s2, fmaf(-mu, s2, bv.z));
    res.w = fmaf(e[3], s3, fmaf(-mu, s3, bv.w));
    *reinterpret_cast<f32x4*>(o + (size_t)r * 1024) = res;
  }
}

extern "C" void kernel_launch(void* const* d_in, const int* in_sizes, int n_in,
                              void* d_out, int out_size, void* d_ws, size_t ws_size,
                              hipStream_t stream) {
  const int* x = (const int*)d_in[0];
  const float* winds = (const float*)d_in[1];
  const float* pw = (const float*)d_in[2];
  const float* pb = (const float*)d_in[3];
  const float* gamma = (const float*)d_in[4];
  const float* beta = (const float*)d_in[5];
  float* out = (float*)d_out;

  const int rows = in_sizes[0];  // 32768
  wind_one<<<rows / ROWS_PB, 256, 0, stream>>>(x, winds, pw, pb, gamma, beta, out);
}

// Round 17
// 47.223 us; speedup vs baseline: 1.2979x; 1.2979x over previous
//
#include <hip/hip_runtime.h>
#include <math.h>

// WindingEmbedding, fused single kernel, direct per-row reduction.
// rows = 32768 (B=8, S=4096), D=1024, W=8 windings, F=16 feats.
// out[row][d] = ((emb - mu) * rsqrt(var+eps)) * gamma + beta
// emb[row][d] = sum_f feats[row][f] * pw[d][f] + pb[d]
//
// ONE dispatch (each graph-node boundary costs ~5us: R13/R15 arithmetic).
// Direct stats (not analytic): marginal cost over the store loop is sumsq +
// 64-lane butterfly + 1 barrier per 4-row chunk (~2-3us) — vs R16's in-reg
// M at ~20us and the 2-dispatch stats chain at ~10us (kernels+gaps).
// Geometry fixes vs R3 (45.8): 512 blocks x 64 rows (4x less wreg-reload
// traffic, smaller tail), chunk-4 -> er[4][4]=16 regs (R3's er[8][4]=32 drove
// ~165 VGPR -> 2 waves/SIMD), parity double-buffer -> 1 barrier/chunk,
// stores spread across 16 chunks. Regular float4 stores, NO launch-bounds
// clamp, NO nontemporal (R5/R9 ledger).

#define TWO_PI 6.28318530717958647692f
#define INV_VOCAB (1.0f / 50257.0f)
#define INV_D (1.0f / 1024.0f)
#define ROWS_PB 64

typedef float f32x4 __attribute__((ext_vector_type(4)));

__global__ void wind_fused(const int* __restrict__ x,
                           const float* __restrict__ winds,
                           const float* __restrict__ pw,
                           const float* __restrict__ pb,
                           const float* __restrict__ gamma,
                           const float* __restrict__ beta,
                           float* __restrict__ out) {
  __shared__ __align__(16) float feat[ROWS_PB][20];  // 16B-aligned rows, <=2-way
  __shared__ float red[2][4][4][2];  // [chunk parity][wave][rowInChunk][sum|sumsq]

  const int tid = threadIdx.x;
  const int wave = tid >> 6;
  const int lane = tid & 63;
  const int row0 = blockIdx.x * ROWS_PB;

  // this thread's 4 projection rows (dims 4t..4t+3) + bias/affine
  float4 wreg[4][4];
#pragma unroll
  for (int r = 0; r < 4; ++r)
#pragma unroll
    for (int c = 0; c < 4; ++c)
      wreg[r][c] = reinterpret_cast<const float4*>(pw)[(tid * 4 + r) * 4 + c];
  const float4 pbv = reinterpret_cast<const float4*>(pb)[tid];
  const float4 gv = reinterpret_cast<const float4*>(gamma)[tid];
  const float4 bv = reinterpret_cast<const float4*>(beta)[tid];

  // feature tile: 64 rows x 16 feats, 4 sincos/thread
#pragma unroll
  for (int s = 0; s < 4; ++s) {
    const int slot = tid + s * 256;
    const int r = slot >> 4, jj = slot & 15;
    const float tf = (float)x[row0 + r] * INV_VOCAB;
    float sn, cs;
    sincosf(TWO_PI * tf * winds[jj >> 1], &sn, &cs);
    feat[r][jj] = (jj & 1) ? sn : cs;  // [cos0,sin0,cos1,sin1,...]
  }
  __syncthreads();

  // ---- 16 chunks of 4 rows: project -> reduce -> normalize -> store ----
#pragma unroll 2
  for (int h = 0; h < 16; ++h) {
    float er[4][4];
    float sr[4], qr[4];

#pragma unroll
    for (int r = 0; r < 4; ++r) {
      const int rr = h * 4 + r;
      const f32x4 F0 = *reinterpret_cast<const f32x4*>(&feat[rr][0]);
      const f32x4 F1 = *reinterpret_cast<const f32x4*>(&feat[rr][4]);
      const f32x4 F2 = *reinterpret_cast<const f32x4*>(&feat[rr][8]);
      const f32x4 F3 = *reinterpret_cast<const f32x4*>(&feat[rr][12]);
#pragma unroll
      for (int k = 0; k < 4; ++k) {
        float a = (k == 0) ? pbv.x : (k == 1) ? pbv.y : (k == 2) ? pbv.z : pbv.w;
        a = fmaf(wreg[k][0].x, F0.x, a);
        a = fmaf(wreg[k][0].y, F0.y, a);
        a = fmaf(wreg[k][0].z, F0.z, a);
        a = fmaf(wreg[k][0].w, F0.w, a);
        a = fmaf(wreg[k][1].x, F1.x, a);
        a = fmaf(wreg[k][1].y, F1.y, a);
        a = fmaf(wreg[k][1].z, F1.z, a);
        a = fmaf(wreg[k][1].w, F1.w, a);
        a = fmaf(wreg[k][2].x, F2.x, a);
        a = fmaf(wreg[k][2].y, F2.y, a);
        a = fmaf(wreg[k][2].z, F2.z, a);
        a = fmaf(wreg[k][2].w, F2.w, a);
        a = fmaf(wreg[k][3].x, F3.x, a);
        a = fmaf(wreg[k][3].y, F3.y, a);
        a = fmaf(wreg[k][3].z, F3.z, a);
        a = fmaf(wreg[k][3].w, F3.w, a);
        er[r][k] = a;
      }
      sr[r] = (er[r][0] + er[r][1]) + (er[r][2] + er[r][3]);
      float q = er[r][0] * er[r][0];
      q = fmaf(er[r][1], er[r][1], q);
      q = fmaf(er[r][2], er[r][2], q);
      q = fmaf(er[r][3], er[r][3], q);
      qr[r] = q;
    }

    // 64-lane butterfly (4 independent rows for ILP)
#pragma unroll
    for (int r = 0; r < 4; ++r) {
#pragma unroll
      for (int off = 1; off < 64; off <<= 1) {
        sr[r] += __shfl_xor(sr[r], off);
        qr[r] += __shfl_xor(qr[r], off);
      }
    }
    if (lane == 0) {
#pragma unroll
      for (int r = 0; r < 4; ++r) {
        red[h & 1][wave][r][0] = sr[r];
        red[h & 1][wave][r][1] = qr[r];
      }
    }
    __syncthreads();  // orders this parity buffer's writes before reads;
                      // next reuse of the buffer is fenced by the intervening
                      // chunk's barrier.

    // finalize + coalesced float4 store (er still live in registers)
    float* o = out + (size_t)(row0 + h * 4) * 1024 + tid * 4;
#pragma unroll
    for (int r = 0; r < 4; ++r) {
      const float s = (red[h & 1][0][r][0] + red[h & 1][1][r][0]) +
                      (red[h & 1][2][r][0] + red[h & 1][3][r][0]);
      const float q = (red[h & 1][0][r][1] + red[h & 1][1][r][1]) +
                      (red[h & 1][2][r][1] + red[h & 1][3][r][1]);
      const float mu = s * INV_D;
      const float var = fmaf(q, INV_D, -mu * mu);
      const float rs = rsqrtf(var + 1e-5f);
      const float s0 = gv.x * rs, s1 = gv.y * rs, s2 = gv.z * rs, s3 = gv.w * rs;
      f32x4 res;
      res.x = fmaf(er[r][0], s0, fmaf(-mu, s0, bv.x));
      res.y = fmaf(er[r][1], s1, fmaf(-mu, s1, bv.y));
      res.z = fmaf(er[r][2], s2, fmaf(-mu, s2, bv.z));
      res.w = fmaf(er[r][3], s3, fmaf(-mu, s3, bv.w));
      *reinterpret_cast<f32x4*>(o + (size_t)r * 1024) = res;
    }
  }
}

extern "C" void kernel_launch(void* const* d_in, const int* in_sizes, int n_in,
                              void* d_out, int out_size, void* d_ws, size_t ws_size,
                              hipStream_t stream) {
  const int* x = (const int*)d_in[0];
  const float* winds = (const float*)d_in[1];
  const float* pw = (const float*)d_in[2];
  const float* pb = (const float*)d_in[3];
  const float* gamma = (const float*)d_in[4];
  const float* beta = (const float*)d_in[5];
  float* out = (float*)d_out;

  const int rows = in_sizes[0];  // 32768
  wind_fused<<<rows / ROWS_PB, 256, 0, stream>>>(x, winds, pw, pb, gamma, beta, out);
}

// Round 18
// 40.701 us; speedup vs baseline: 1.5058x; 1.1603x over previous
//
#include <hip/hip_runtime.h>
#include <math.h>

// WindingEmbedding: rows = 32768 (B=8, S=4096), D=1024, W=8 windings, F=16 feats.
// out[row][d] = ((emb - mu) * rsqrt(var+eps)) * gamma + beta
// emb[row][d] = sum_f feats[row][f] * pw[d][f] + pb[d]
//
// Analytic LayerNorm stats:
//   mu = f.meanW + mean_b ; E[e^2] = f'Mf + 2 f.c + mean_b2 ; var = E[e^2]-mu^2
// with M = (1/D) W'W, meanW = (1/D) W'1, c = (1/D) W'b.
//
// FINAL (best = R15, 40.6us). Structure: 64-block stats_partial -> 1-block
// stats_reduce -> 512-block main (64 rows, 4 dims/thread, float4 stores).
// Ledger of failed alternatives: fused-direct 45.8/50.4/47.2 (per-chunk
// barriers drain store pipe); fused-analytic-in-reg 61.3 (~20us redundant M
// per block); all-blocks partial-fold 52.9/49.1 (cross-XCD reads); spin-flag
// fences 52.1/54.3; cooperative grid.sync 186.7 (~70us/sync); 1-CU stats
// 95/54.4 (latency chains); NT stores +8-10us everywhere tried.
// Remaining gap to the 19us pure-store floor: ~10us graph-node boundaries
// + ~5.5us stats chain + ~5us main prologue — all structurally locked.

#define TWO_PI 6.28318530717958647692f
#define INV_VOCAB (1.0f / 50257.0f)
#define INV_D (1.0f / 1024.0f)
#define ROWS_PB 64
#define PSTRIDE 320
#define FINAL_OFF 20480

typedef float f32x4 __attribute__((ext_vector_type(4)));

// ---------- stats partial: 64 blocks, block b covers d in [16b, 16b+16) ----------
__global__ __launch_bounds__(256) void stats_partial(const float* __restrict__ pw,
                                                     const float* __restrict__ pb,
                                                     float* __restrict__ ws) {
  const int t = threadIdx.x;
  const int b = blockIdx.x;
  const int f = t >> 4, g = t & 15;
  const int d0 = b * 16;

  float m = 0.f, mw = 0.f, cc = 0.f, b1 = 0.f, b2 = 0.f;
#pragma unroll
  for (int k = 0; k < 16; ++k) {
    const int d = d0 + k;
    const float wf = pw[d * 16 + f];
    const float wg = pw[d * 16 + g];
    m = fmaf(wf, wg, m);
    if (g == 0) {
      const float bb = pb[d];
      mw += wf;
      cc = fmaf(wf, bb, cc);
      if (f == 0) {
        b1 += bb;
        b2 = fmaf(bb, bb, b2);
      }
    }
  }
  float* p = ws + b * PSTRIDE;
  p[t] = m * INV_D;
  if (g == 0) {
    p[256 + f] = mw * INV_D;
    p[272 + f] = cc * INV_D;
    if (f == 0) {
      p[288] = b1 * INV_D;
      p[289] = b2 * INV_D;
    }
  }
}

// ---------- stats reduce: 1 block, 320 threads, 64 partials each ----------
__global__ __launch_bounds__(320) void stats_reduce(float* __restrict__ ws) {
  const int t = threadIdx.x;  // only 0..289 meaningful
  float s = 0.f;
#pragma unroll
  for (int b = 0; b < 64; ++b) s += ws[b * PSTRIDE + t];
  ws[FINAL_OFF + t] = s;
}

// ---------- main: 512 row-blocks, 256 thr, 4 dims/thread, 64 rows ----------
__global__ __launch_bounds__(256) void wind_main(const int* __restrict__ x,
                                                 const float* __restrict__ winds,
                                                 const float* __restrict__ pw,
                                                 const float* __restrict__ pb,
                                                 const float* __restrict__ gamma,
                                                 const float* __restrict__ beta,
                                                 const float* __restrict__ ws,
                                                 float* __restrict__ out) {
  __shared__ __align__(16) float feat[ROWS_PB][20];  // stride 20: 16B-aligned, <=2-way
  __shared__ __align__(16) float Mlds[16][20];       // b128-loadable rows
  __shared__ float mwl[16], cl[16], cst[2];
  __shared__ float murs[ROWS_PB][2];

  const int tid = threadIdx.x;
  const int row0 = blockIdx.x * ROWS_PB;

  // stage analytic-stats finals (1.2 KB)
  Mlds[tid >> 4][tid & 15] = ws[FINAL_OFF + tid];
  if (tid < 16) mwl[tid] = ws[FINAL_OFF + 256 + tid];
  else if (tid < 32) cl[tid - 16] = ws[FINAL_OFF + 256 + tid];
  else if (tid < 34) cst[tid - 32] = ws[FINAL_OFF + 256 + tid];

  // this thread's 4 projection rows (dims 4t..4t+3) + bias/affine
  float4 wreg[4][4];
#pragma unroll
  for (int r = 0; r < 4; ++r)
#pragma unroll
    for (int c = 0; c < 4; ++c)
      wreg[r][c] = reinterpret_cast<const float4*>(pw)[(tid * 4 + r) * 4 + c];
  const float4 pbv = reinterpret_cast<const float4*>(pb)[tid];
  const float4 gv = reinterpret_cast<const float4*>(gamma)[tid];
  const float4 bv = reinterpret_cast<const float4*>(beta)[tid];

  // feature tile: 64 rows x 16 feats, 4 slots (sincos) per thread
#pragma unroll
  for (int s = 0; s < 4; ++s) {
    const int slot = tid + s * 256;
    const int r = slot >> 4, jj = slot & 15;
    const float tf = (float)x[row0 + r] * INV_VOCAB;
    float sn, cs;
    sincosf(TWO_PI * tf * winds[jj >> 1], &sn, &cs);
    feat[r][jj] = (jj & 1) ? sn : cs;  // [cos0,sin0,cos1,sin1,...]
  }
  __syncthreads();

  // per-row stats: 16-lane group per row, 4 rows per thread, in-wave shuffle
  {
    const int jj = tid & 15;
    const float mwj = mwl[jj];
    const float cj = cl[jj];
    const f32x4 M0 = *reinterpret_cast<const f32x4*>(&Mlds[jj][0]);
    const f32x4 M1 = *reinterpret_cast<const f32x4*>(&Mlds[jj][4]);
    const f32x4 M2 = *reinterpret_cast<const f32x4*>(&Mlds[jj][8]);
    const f32x4 M3 = *reinterpret_cast<const f32x4*>(&Mlds[jj][12]);
#pragma unroll
    for (int h = 0; h < 4; ++h) {
      const int r = (tid >> 4) + h * 16;
      const f32x4 F0 = *reinterpret_cast<const f32x4*>(&feat[r][0]);
      const f32x4 F1 = *reinterpret_cast<const f32x4*>(&feat[r][4]);
      const f32x4 F2 = *reinterpret_cast<const f32x4*>(&feat[r][8]);
      const f32x4 F3 = *reinterpret_cast<const f32x4*>(&feat[r][12]);
      float acc = 0.f;
      acc = fmaf(M0.x, F0.x, acc); acc = fmaf(M0.y, F0.y, acc);
      acc = fmaf(M0.z, F0.z, acc); acc = fmaf(M0.w, F0.w, acc);
      acc = fmaf(M1.x, F1.x, acc); acc = fmaf(M1.y, F1.y, acc);
      acc = fmaf(M1.z, F1.z, acc); acc = fmaf(M1.w, F1.w, acc);
      acc = fmaf(M2.x, F2.x, acc); acc = fmaf(M2.y, F2.y, acc);
      acc = fmaf(M2.z, F2.z, acc); acc = fmaf(M2.w, F2.w, acc);
      acc = fmaf(M3.x, F3.x, acc); acc = fmaf(M3.y, F3.y, acc);
      acc = fmaf(M3.z, F3.z, acc); acc = fmaf(M3.w, F3.w, acc);
      const float fjj = feat[r][jj];
      float pE = fjj * fmaf(2.f, cj, acc);
      float pM = fjj * mwj;
#pragma unroll
      for (int off = 1; off < 16; off <<= 1) {
        pE += __shfl_xor(pE, off);
        pM += __shfl_xor(pM, off);
      }
      if (jj == 0) {
        const float mu = pM + cst[0];
        const float var = (pE + cst[1]) - mu * mu;
        murs[r][0] = mu;
        murs[r][1] = rsqrtf(var + 1e-5f);
      }
    }
  }
  __syncthreads();

  // main loop: 64 rows x 4 dims/thread; broadcast feat reads, float4 stores
  float* o = out + (size_t)row0 * 1024 + tid * 4;
#pragma unroll 2
  for (int r = 0; r < ROWS_PB; ++r) {
    const f32x4 F0 = *reinterpret_cast<const f32x4*>(&feat[r][0]);
    const f32x4 F1 = *reinterpret_cast<const f32x4*>(&feat[r][4]);
    const f32x4 F2 = *reinterpret_cast<const f32x4*>(&feat[r][8]);
    const f32x4 F3 = *reinterpret_cast<const f32x4*>(&feat[r][12]);
    float e[4];
#pragma unroll
    for (int k = 0; k < 4; ++k) {
      float a = (k == 0) ? pbv.x : (k == 1) ? pbv.y : (k == 2) ? pbv.z : pbv.w;
      a = fmaf(wreg[k][0].x, F0.x, a);
      a = fmaf(wreg[k][0].y, F0.y, a);
      a = fmaf(wreg[k][0].z, F0.z, a);
      a = fmaf(wreg[k][0].w, F0.w, a);
      a = fmaf(wreg[k][1].x, F1.x, a);
      a = fmaf(wreg[k][1].y, F1.y, a);
      a = fmaf(wreg[k][1].z, F1.z, a);
      a = fmaf(wreg[k][1].w, F1.w, a);
      a = fmaf(wreg[k][2].x, F2.x, a);
      a = fmaf(wreg[k][2].y, F2.y, a);
      a = fmaf(wreg[k][2].z, F2.z, a);
      a = fmaf(wreg[k][2].w, F2.w, a);
      a = fmaf(wreg[k][3].x, F3.x, a);
      a = fmaf(wreg[k][3].y, F3.y, a);
      a = fmaf(wreg[k][3].z, F3.z, a);
      a = fmaf(wreg[k][3].w, F3.w, a);
      e[k] = a;
    }
    const float mu = murs[r][0];
    const float rs = murs[r][1];
    const float s0 = gv.x * rs, s1 = gv.y * rs, s2 = gv.z * rs, s3 = gv.w * rs;
    f32x4 res;
    res.x = fmaf(e[0], s0, fmaf(-mu, s0, bv.x));
    res.y = fmaf(e[1], s1, fmaf(-mu, s1, bv.y));
    res.z = fmaf(e[2], s2, fmaf(-mu, s2, bv.z));
    res.w = fmaf(e[3], s3, fmaf(-mu, s3, bv.w));
    *reinterpret_cast<f32x4*>(o + (size_t)r * 1024) = res;
  }
}

extern "C" void kernel_launch(void* const* d_in, const int* in_sizes, int n_in,
                              void* d_out, int out_size, void* d_ws, size_t ws_size,
                              hipStream_t stream) {
  const int* x = (const int*)d_in[0];
  const float* winds = (const float*)d_in[1];
  const float* pw = (const float*)d_in[2];
  const float* pb = (const float*)d_in[3];
  const float* gamma = (const float*)d_in[4];
  const float* beta = (const float*)d_in[5];
  float* out = (float*)d_out;
  float* ws = (float*)d_ws;

  const int rows = in_sizes[0];  // 32768
  stats_partial<<<64, 256, 0, stream>>>(pw, pb, ws);
  stats_reduce<<<1, 320, 0, stream>>>(ws);
  wind_main<<<rows / ROWS_PB, 256, 0, stream>>>(x, winds, pw, pb, gamma, beta,
                                                ws, out);
}